// Round 10
// baseline (515.427 us; speedup 1.0000x reference)
//
#include <hip/hip_runtime.h>
#include <stdint.h>

typedef short bf16x8 __attribute__((ext_vector_type(8)));
typedef float f32x4  __attribute__((ext_vector_type(4)));

#define GLOAD_LDS16(gp, lp) \
    __builtin_amdgcn_global_load_lds((const __attribute__((address_space(1))) void*)(gp), \
                                     (__attribute__((address_space(3))) void*)(lp), 16, 0, 0)

__device__ __forceinline__ uint32_t bfbits(float f) {
    uint32_t u = __builtin_bit_cast(uint32_t, f);
    u += 0x7FFFu + ((u >> 16) & 1u);   // round-to-nearest-even
    return u >> 16;
}
__device__ __forceinline__ uint32_t pk2(float a, float b) {
    return bfbits(a) | (bfbits(b) << 16);
}

// x (f32, [16][192][192][64]) -> xb (bf16, PADDED [16][194][194][64], zero halo)
__global__ void xcvt_kernel(const float* __restrict__ x, short* __restrict__ xb) {
    const int total = 16 * 194 * 194 * 8;          // 16B chunks
    for (int i = blockIdx.x * 256 + threadIdx.x; i < total; i += gridDim.x * 256) {
        int g  = i & 7;
        int t  = i >> 3;
        int wp = t % 194; t /= 194;
        int hp = t % 194;
        int nn = t / 194;
        uint4 r = {0u, 0u, 0u, 0u};
        if (hp >= 1 && hp <= 192 && wp >= 1 && wp <= 192) {
            const float* s = x + (((size_t)nn * 192 + (hp - 1)) * 192 + (wp - 1)) * 64 + g * 8;
            f32x4 a = *(const f32x4*)s;
            f32x4 b = *(const f32x4*)(s + 4);
            r.x = pk2(a[0], a[1]); r.y = pk2(a[2], a[3]);
            r.z = pk2(b[0], b[1]); r.w = pk2(b[2], b[3]);
        }
        *(uint4*)(xb + (size_t)i * 8) = r;
    }
}

// Wt[t][c][j][ic] = bf16(W[dy][dx][ic][j*4+c]); quadrant c owns oc = j*4+c.
__global__ void wt_kernel(const float* __restrict__ W, short* __restrict__ Wt) {
    int idx = blockIdx.x * 256 + threadIdx.x;      // 9*4*64*64 = 147456
    if (idx >= 147456) return;
    int t  = idx >> 14;
    int r  = idx & 16383;
    int c  = r >> 12;
    int j  = (r >> 6) & 63;
    int ic = r & 63;
    Wt[idx] = (short)bfbits(W[(t * 64 + ic) * 256 + j * 4 + c]);
}

#define NT 6
#define RING 18
#define A_SLOT 4224              // shorts per h-row slot: 66 wpos * 64 ic (8448 B)
#define A_SH   (RING * A_SLOT)   // 152,064 B — LDS holds ONLY the A ring

// Implicit-GEMM conv3x3 + bias + pixel_shuffle quadrant, bf16 MFMA.
// Wave = 1 h-row x 64 w x 64 j. B lives in REGISTERS (double-buffered per tap,
// streamed from L2-resident Wt) -> LDS reads are A-only (0.25 ds_read/MFMA).
// A ring = 18 slots: 10 live + 8 free, so next tile's refill (global_load_lds)
// issues at TILE START into free slots and hides under compute. ONE barrier
// per tile; vmcnt(63) guarantees refills (oldest) done without draining stores.
__global__ __launch_bounds__(512, 2) void conv_ps_kernel(
    const short* __restrict__ xb, const short* __restrict__ Wt,
    const float* __restrict__ bias, float* __restrict__ out)
{
    __shared__ short As[A_SH];

    const int tid   = threadIdx.x;
    const int lane  = tid & 63;
    const int wv    = tid >> 6;       // which of 8 h-rows in the tile
    const int row_l = lane & 15;
    const int grp   = lane >> 4;

    // XCD-aware bijective swizzle (nwg = 768 % 8 == 0); c innermost.
    const int raw = blockIdx.x;
    const int lb  = (raw & 7) * 96 + (raw >> 3);
    const int c   = lb & 3;
    const int wt  = (lb >> 2) % 3;
    const int hg  = (lb / 12) & 3;
    const int n   = lb / 48;
    const int w0  = wt * 64;
    const int hbase = hg * 48;
    const int q = c & 1, p = (c >> 1) & 1;

    const short* wsrc = Wt + c * 4096;             // [t][c][j][ic], t-stride 16384

    // ---- prologue: A ring rows hbase-1 .. hbase+8 (10 rows x 9 instrs) ----
    for (int k = wv; k < 90; k += 8) {
        int rl  = k / 9, jj = k % 9;
        int row = hbase - 1 + rl;
        int slot = (row + 1) % RING;
        int cch = jj * 64 + lane;                  // 0..575 (valid < 528)
        int wpos = cch >> 3, g1 = cch & 7;
        int gs   = g1 ^ (wpos & 7);                // pre-swizzled source slot
        const short* src = xb + (((size_t)n * 194 + (row + 1)) * 194 + (w0 + wpos)) * 64 + gs * 8;
        void* dst = (char*)As + slot * 8448 + jj * 1024;
        if (jj < 8)            GLOAD_LDS16(src, dst);
        else if (lane < 16)    GLOAD_LDS16(src, dst);   // partial: 16 chunks
    }
    __syncthreads();   // drains vmcnt -> prologue LDS complete

    float bv[4];
    #pragma unroll
    for (int nt = 0; nt < 4; ++nt)
        bv[nt] = bias[(nt * 16 + row_l) * 4 + c];

    bf16x8 bA[2][4], bB[2][4];    // B tap double-buffer (registers)

#define LOADB(DST, T) do { \
    _Pragma("unroll") for (int ks = 0; ks < 2; ++ks) \
        _Pragma("unroll") for (int nt_ = 0; nt_ < 4; ++nt_) \
            DST[ks][nt_] = *(const bf16x8*)(wsrc + (T) * 16384 + \
                             (nt_ * 16 + row_l) * 64 + (ks * 4 + grp) * 8); \
} while (0)

#define TAP(T, CUR, NXT, LOADNEXT) do { \
    const int dy_ = (T) / 3, dx_ = (T) % 3; \
    const int rd_ = row_l + dx_; \
    const int a7_ = rd_ & 7; \
    const int aB_ = sl[dy_] * A_SLOT + rd_ * 64; \
    bf16x8 af[2][4]; \
    _Pragma("unroll") for (int ks = 0; ks < 2; ++ks) { \
        const short* ap = &As[aB_ + (((ks * 4 + grp) ^ a7_) << 3)]; \
        _Pragma("unroll") for (int mt_ = 0; mt_ < 4; ++mt_) \
            af[ks][mt_] = *(const bf16x8*)(ap + mt_ * 1024); \
    } \
    if (LOADNEXT) LOADB(NXT, (T) + 1); \
    _Pragma("unroll") for (int ks = 0; ks < 2; ++ks) \
        _Pragma("unroll") for (int mt_ = 0; mt_ < 4; ++mt_) \
            _Pragma("unroll") for (int nt_ = 0; nt_ < 4; ++nt_) \
                acc[mt_][nt_] = __builtin_amdgcn_mfma_f32_16x16x32_bf16( \
                    af[ks][mt_], CUR[ks][nt_], acc[mt_][nt_], 0, 0, 0); \
} while (0)

    #pragma unroll 1
    for (int it = 0; it < NT; ++it) {
        const int h0 = hbase + it * 8;

        // 1. issue next tile's refill FIRST (rows h0+9..h0+16 -> free slots);
        //    HBM latency hides under this tile's entire compute.
        if (it < NT - 1) {
            for (int k = wv; k < 72; k += 8) {
                int rl  = k / 9, jj = k % 9;
                int row = h0 + 9 + rl;
                int slot = (row + 1) % RING;
                int cch = jj * 64 + lane;
                int wpos = cch >> 3, g1 = cch & 7;
                int gs   = g1 ^ (wpos & 7);
                const short* src = xb + (((size_t)n * 194 + (row + 1)) * 194 + (w0 + wpos)) * 64 + gs * 8;
                void* dst = (char*)As + slot * 8448 + jj * 1024;
                if (jj < 8)         GLOAD_LDS16(src, dst);
                else if (lane < 16) GLOAD_LDS16(src, dst);
            }
        }

        // 2. tap-0 B fragments
        LOADB(bA, 0);

        // 3. acc starts at bias (fused bias add)
        f32x4 acc[4][4];
        #pragma unroll
        for (int i = 0; i < 4; ++i)
            #pragma unroll
            for (int j = 0; j < 4; ++j)
                acc[i][j] = (f32x4){bv[j], bv[j], bv[j], bv[j]};

        int sl[3];
        #pragma unroll
        for (int dy = 0; dy < 3; ++dy) sl[dy] = (h0 + wv + dy) % RING;

        // 4. 9 taps, B double-buffered: even taps use bA, odd use bB
        TAP(0, bA, bB, 1);
        TAP(1, bB, bA, 1);
        TAP(2, bA, bB, 1);
        TAP(3, bB, bA, 1);
        TAP(4, bA, bB, 1);
        TAP(5, bB, bA, 1);
        TAP(6, bA, bB, 1);
        TAP(7, bB, bA, 1);
        TAP(8, bA, bB, 0);

        // 5. stores: issue; they drain under the next tile's compute
        {
            const int h = h0 + wv;
            const long rowb = ((long)(n * 384 + 2 * h + q)) * 384;
            #pragma unroll
            for (int mt = 0; mt < 4; ++mt) {
                float* po = out + ((rowb + 2 * (w0 + mt * 16 + grp * 4) + p) * 64 + row_l);
                #pragma unroll
                for (int nt = 0; nt < 4; ++nt)
                    #pragma unroll
                    for (int jv = 0; jv < 4; ++jv)
                        po[jv * 128 + nt * 16] = acc[mt][nt][jv];
            }
        }

        // 6. ONE barrier per tile. vmcnt(63): the refills are this wave's
        //    oldest VMEM ops -> guaranteed complete; <=63 stores stay in flight.
        if (it < NT - 1) {
            asm volatile("s_waitcnt vmcnt(63)" ::: "memory");
            __builtin_amdgcn_sched_barrier(0);
            __builtin_amdgcn_s_barrier();
            __builtin_amdgcn_sched_barrier(0);
        }
    }
#undef TAP
#undef LOADB
}

extern "C" void kernel_launch(void* const* d_in, const int* in_sizes, int n_in,
                              void* d_out, int out_size, void* d_ws, size_t ws_size,
                              hipStream_t stream) {
    const float* x = (const float*)d_in[0];
    const float* W = (const float*)d_in[1];
    const float* b = (const float*)d_in[2];
    float* out = (float*)d_out;

    const size_t xb_bytes = (size_t)16 * 194 * 194 * 64 * 2;   // 77,070,336 (padded)
    short* xbuf = (short*)d_ws;
    short* Wt   = (short*)((char*)d_ws + xb_bytes);

    hipLaunchKernelGGL(xcvt_kernel, dim3(2048), dim3(256), 0, stream, x, xbuf);
    hipLaunchKernelGGL(wt_kernel, dim3(576), dim3(256), 0, stream, W, Wt);
    hipLaunchKernelGGL(conv_ps_kernel, dim3(768), dim3(512), 0, stream, xbuf, Wt, b, out);
}

// Round 11
// 292.883 us; speedup vs baseline: 1.7598x; 1.7598x over previous
//
#include <hip/hip_runtime.h>
#include <stdint.h>

typedef short bf16x8 __attribute__((ext_vector_type(8)));
typedef float f32x4  __attribute__((ext_vector_type(4)));

#define GLOAD_LDS16(gp, lp) \
    __builtin_amdgcn_global_load_lds((const __attribute__((address_space(1))) void*)(gp), \
                                     (__attribute__((address_space(3))) void*)(lp), 16, 0, 0)

__device__ __forceinline__ uint32_t bfbits(float f) {
    uint32_t u = __builtin_bit_cast(uint32_t, f);
    u += 0x7FFFu + ((u >> 16) & 1u);   // round-to-nearest-even
    return u >> 16;
}
__device__ __forceinline__ uint32_t pk2(float a, float b) {
    return bfbits(a) | (bfbits(b) << 16);
}

// x (f32, [16][192][192][64]) -> xb (bf16, PADDED [16][194][194][64], zero halo)
__global__ void xcvt_kernel(const float* __restrict__ x, short* __restrict__ xb) {
    const int total = 16 * 194 * 194 * 8;          // 16B chunks
    for (int i = blockIdx.x * 256 + threadIdx.x; i < total; i += gridDim.x * 256) {
        int g  = i & 7;
        int t  = i >> 3;
        int wp = t % 194; t /= 194;
        int hp = t % 194;
        int nn = t / 194;
        uint4 r = {0u, 0u, 0u, 0u};
        if (hp >= 1 && hp <= 192 && wp >= 1 && wp <= 192) {
            const float* s = x + (((size_t)nn * 192 + (hp - 1)) * 192 + (wp - 1)) * 64 + g * 8;
            f32x4 a = *(const f32x4*)s;
            f32x4 b = *(const f32x4*)(s + 4);
            r.x = pk2(a[0], a[1]); r.y = pk2(a[2], a[3]);
            r.z = pk2(b[0], b[1]); r.w = pk2(b[2], b[3]);
        }
        *(uint4*)(xb + (size_t)i * 8) = r;
    }
}

// Wt[t][c][j][ic] = bf16(W[dy][dx][ic][j*4+c]); quadrant c owns oc = j*4+c.
__global__ void wt_kernel(const float* __restrict__ W, short* __restrict__ Wt) {
    int idx = blockIdx.x * 256 + threadIdx.x;      // 9*4*64*64 = 147456
    if (idx >= 147456) return;
    int t  = idx >> 14;
    int r  = idx & 16383;
    int c  = r >> 12;
    int j  = (r >> 6) & 63;
    int ic = r & 63;
    Wt[idx] = (short)bfbits(W[(t * 64 + ic) * 256 + j * 4 + c]);
}

#define NT 6
#define RING 10
#define A_SLOT 4224              // shorts per h-row slot: 66 wpos * 64 ic (8448 B)
#define A_SH   (RING * A_SLOT)   // 84,480 B
#define B_SH   (9 * 64 * 64)     // 73,728 B
// total 158,208 B -> 1 block/CU (8 waves, 2/SIMD)

// Implicit-GEMM conv3x3 + bias + pixel_shuffle quadrant, bf16 MFMA.
// Wave = 1 h-row x 64 w x 64 j, 0.5 ds_read/MFMA. OPERAND-SWAPPED MFMA
// (mfma(B,A)) -> D is [j][w]: per-lane f32x4 = contiguous j-quad, so the
// epilogue is 16 global_store_dwordx4 (1KB/instr) instead of 64 scalars.
__global__ __launch_bounds__(512, 2) void conv_ps_kernel(
    const short* __restrict__ xb, const short* __restrict__ Wt,
    const float* __restrict__ bias, float* __restrict__ out)
{
    __shared__ short smem[A_SH + B_SH];
    short* As = smem;
    short* Bs = smem + A_SH;

    const int tid   = threadIdx.x;
    const int lane  = tid & 63;
    const int wv    = tid >> 6;       // which of 8 h-rows in the tile
    const int row_l = lane & 15;
    const int grp   = lane >> 4;
    const int b7    = row_l & 7;

    // XCD-aware bijective swizzle (nwg = 768 % 8 == 0); c innermost.
    const int raw = blockIdx.x;
    const int lb  = (raw & 7) * 96 + (raw >> 3);
    const int c   = lb & 3;
    const int wt  = (lb >> 2) % 3;
    const int hg  = (lb / 12) & 3;
    const int n   = lb / 48;
    const int w0  = wt * 64;
    const int hbase = hg * 48;
    const int q = c & 1, p = (c >> 1) & 1;

    // ---- prologue: B via global_load_lds (9 taps x 512 chunks = 72 instrs) ----
    {
        const short* wsrc = Wt + c * 4096;         // [t][c][j][ic], t-stride 16384
        for (int k = wv; k < 72; k += 8) {
            int t   = k >> 3, j8 = k & 7;
            int cch = j8 * 64 + lane;
            int j   = cch >> 3, s1 = cch & 7;
            int ss  = s1 ^ (j & 7);                // pre-swizzled source slot
            GLOAD_LDS16(wsrc + t * 16384 + j * 64 + ss * 8,
                        (char*)Bs + t * 8192 + j8 * 1024);
        }
    }
    // ---- prologue: A ring rows hbase-1 .. hbase+8 (10 rows x 9 instrs) ----
    for (int k = wv; k < 90; k += 8) {
        int rl  = k / 9, jj = k % 9;
        int row = hbase - 1 + rl;
        int slot = (row + 1) % RING;
        int cch = jj * 64 + lane;                  // 0..575 (valid < 528)
        int wpos = cch >> 3, g1 = cch & 7;
        int gs   = g1 ^ (wpos & 7);
        const short* src = xb + (((size_t)n * 194 + (row + 1)) * 194 + (w0 + wpos)) * 64 + gs * 8;
        void* dst = (char*)As + slot * 8448 + jj * 1024;
        if (jj < 8)            GLOAD_LDS16(src, dst);
        else if (lane < 16)    GLOAD_LDS16(src, dst);   // partial: 16 chunks
    }
    __syncthreads();   // drains vmcnt -> prologue LDS complete

    // bias vector per nt: j0 = nt*16 + grp*4, components j0..j0+3 (oc = j*4+c)
    f32x4 bv4[4];
    #pragma unroll
    for (int nt = 0; nt < 4; ++nt) {
        const int j0 = nt * 16 + grp * 4;
        #pragma unroll
        for (int jv = 0; jv < 4; ++jv)
            bv4[nt][jv] = bias[(j0 + jv) * 4 + c];
    }

    #pragma unroll 1
    for (int it = 0; it < NT; ++it) {
        const int h0 = hbase + it * 8;

        // acc starts at bias (fused bias add); acc[mt][nt] = j-quad
        f32x4 acc[4][4];
        #pragma unroll
        for (int i = 0; i < 4; ++i)
            #pragma unroll
            for (int j = 0; j < 4; ++j)
                acc[i][j] = bv4[j];

        // compute: full K=576 for this wave's 64x64 tile, barrier-free
        int sl[3];
        #pragma unroll
        for (int dy = 0; dy < 3; ++dy) sl[dy] = (h0 + wv + dy) % RING;

        #pragma unroll
        for (int dy = 0; dy < 3; ++dy) {
            #pragma unroll
            for (int dx = 0; dx < 3; ++dx) {
                const int t  = dy * 3 + dx;
                const int rd = row_l + dx;
                const int a7 = rd & 7;
                const int aB = sl[dy] * A_SLOT + rd * 64;
                const int bB = t * 4096 + row_l * 64;
                #pragma unroll
                for (int ks = 0; ks < 2; ++ks) {
                    const int kg = ks * 4 + grp;
                    const short* ap = &As[aB + ((kg ^ a7) << 3)];
                    const short* bp = &Bs[bB + ((kg ^ b7) << 3)];
                    bf16x8 af[4], bfr[4];
                    #pragma unroll
                    for (int mt = 0; mt < 4; ++mt) af[mt]  = *(const bf16x8*)(ap + mt * 1024);
                    #pragma unroll
                    for (int nt = 0; nt < 4; ++nt) bfr[nt] = *(const bf16x8*)(bp + nt * 1024);
                    // swapped operands: D[j][w] so per-lane f32x4 is a j-quad
                    #pragma unroll
                    for (int mt = 0; mt < 4; ++mt)
                        #pragma unroll
                        for (int nt = 0; nt < 4; ++nt)
                            acc[mt][nt] = __builtin_amdgcn_mfma_f32_16x16x32_bf16(
                                bfr[nt], af[mt], acc[mt][nt], 0, 0, 0);
                }
            }
        }

        const int h = h0 + wv;
        const long rowb = ((long)(n * 384 + 2 * h + q)) * 384;

        if (it < NT - 1) {
            // 1. all waves done READING the ring
            asm volatile("s_waitcnt lgkmcnt(0)" ::: "memory");
            __builtin_amdgcn_sched_barrier(0);
            __builtin_amdgcn_s_barrier();
            __builtin_amdgcn_sched_barrier(0);

            // 2. issue refill: rows h0+9 .. h0+16 (8 rows x 9 instrs = 72)
            for (int k = wv; k < 72; k += 8) {
                int rl  = k / 9, jj = k % 9;
                int row = h0 + 9 + rl;
                int slot = (row + 1) % RING;
                int cch = jj * 64 + lane;
                int wpos = cch >> 3, g1 = cch & 7;
                int gs   = g1 ^ (wpos & 7);
                const short* src = xb + (((size_t)n * 194 + (row + 1)) * 194 + (w0 + wpos)) * 64 + gs * 8;
                void* dst = (char*)As + slot * 8448 + jj * 1024;
                if (jj < 8)         GLOAD_LDS16(src, dst);
                else if (lane < 16) GLOAD_LDS16(src, dst);
            }
            asm volatile("" ::: "memory");
            __builtin_amdgcn_sched_barrier(0);

            // 3. epilogue: 16 dwordx4 stores (j-contiguous), no transpose needed
            #pragma unroll
            for (int mt = 0; mt < 4; ++mt) {
                float* po = out + ((rowb + 2 * (w0 + mt * 16 + row_l) + p) * 64 + grp * 4);
                #pragma unroll
                for (int nt = 0; nt < 4; ++nt)
                    *(f32x4*)(po + nt * 16) = acc[mt][nt];
            }

            // 4. wait refills only (oldest 9 of this wave's VMEM ops)
            asm volatile("s_waitcnt vmcnt(15)" ::: "memory");
            __builtin_amdgcn_sched_barrier(0);
            __builtin_amdgcn_s_barrier();          // refilled rows visible
            __builtin_amdgcn_sched_barrier(0);
        } else {
            #pragma unroll
            for (int mt = 0; mt < 4; ++mt) {
                float* po = out + ((rowb + 2 * (w0 + mt * 16 + row_l) + p) * 64 + grp * 4);
                #pragma unroll
                for (int nt = 0; nt < 4; ++nt)
                    *(f32x4*)(po + nt * 16) = acc[mt][nt];
            }
        }
    }
}

extern "C" void kernel_launch(void* const* d_in, const int* in_sizes, int n_in,
                              void* d_out, int out_size, void* d_ws, size_t ws_size,
                              hipStream_t stream) {
    const float* x = (const float*)d_in[0];
    const float* W = (const float*)d_in[1];
    const float* b = (const float*)d_in[2];
    float* out = (float*)d_out;

    const size_t xb_bytes = (size_t)16 * 194 * 194 * 64 * 2;   // 77,070,336 (padded)
    short* xbuf = (short*)d_ws;
    short* Wt   = (short*)((char*)d_ws + xb_bytes);

    hipLaunchKernelGGL(xcvt_kernel, dim3(2048), dim3(256), 0, stream, x, xbuf);
    hipLaunchKernelGGL(wt_kernel, dim3(576), dim3(256), 0, stream, W, Wt);
    hipLaunchKernelGGL(conv_ps_kernel, dim3(768), dim3(512), 0, stream, xbuf, Wt, b, out);
}

// Round 12
// 235.605 us; speedup vs baseline: 2.1877x; 1.2431x over previous
//
#include <hip/hip_runtime.h>
#include <stdint.h>

typedef short bf16x8 __attribute__((ext_vector_type(8)));
typedef float f32x4  __attribute__((ext_vector_type(4)));

#define GLOAD_LDS16(gp, lp) \
    __builtin_amdgcn_global_load_lds((const __attribute__((address_space(1))) void*)(gp), \
                                     (__attribute__((address_space(3))) void*)(lp), 16, 0, 0)

__device__ __forceinline__ uint32_t bfbits(float f) {
    uint32_t u = __builtin_bit_cast(uint32_t, f);
    u += 0x7FFFu + ((u >> 16) & 1u);   // round-to-nearest-even
    return u >> 16;
}
__device__ __forceinline__ uint32_t pk2(float a, float b) {
    return bfbits(a) | (bfbits(b) << 16);
}

// Fused prep: blocks [0,2048) convert x (f32) -> xb (bf16, PADDED
// [16][194][194][64], zero halo) with nontemporal x loads (read-once);
// blocks [2048,2624) build Wt[t][c][j][ic] = bf16(W[dy][dx][ic][j*4+c]).
__global__ void prep_kernel(const float* __restrict__ x, short* __restrict__ xb,
                            const float* __restrict__ W, short* __restrict__ Wt) {
    const int b = blockIdx.x;
    if (b < 2048) {
        const int total = 16 * 194 * 194 * 8;          // 16B chunks
        for (int i = b * 256 + threadIdx.x; i < total; i += 2048 * 256) {
            int g  = i & 7;
            int t  = i >> 3;
            int wp = t % 194; t /= 194;
            int hp = t % 194;
            int nn = t / 194;
            uint4 r = {0u, 0u, 0u, 0u};
            if (hp >= 1 && hp <= 192 && wp >= 1 && wp <= 192) {
                const float* s = x + (((size_t)nn * 192 + (hp - 1)) * 192 + (wp - 1)) * 64 + g * 8;
                f32x4 a = __builtin_nontemporal_load((const f32x4*)s);
                f32x4 bb = __builtin_nontemporal_load((const f32x4*)(s + 4));
                r.x = pk2(a[0], a[1]); r.y = pk2(a[2], a[3]);
                r.z = pk2(bb[0], bb[1]); r.w = pk2(bb[2], bb[3]);
            }
            *(uint4*)(xb + (size_t)i * 8) = r;
        }
    } else {
        int idx = (b - 2048) * 256 + threadIdx.x;      // 9*4*64*64 = 147456
        if (idx < 147456) {
            int t  = idx >> 14;
            int r  = idx & 16383;
            int c  = r >> 12;
            int j  = (r >> 6) & 63;
            int ic = r & 63;
            Wt[idx] = (short)bfbits(W[(t * 64 + ic) * 256 + j * 4 + c]);
        }
    }
}

#define NT 6
#define RING 10
#define A_SLOT 4224              // shorts per h-row slot: 66 wpos * 64 ic (8448 B)
#define A_SH   (RING * A_SLOT)   // 84,480 B
#define B_SH   (9 * 64 * 64)     // 73,728 B
// total 158,208 B -> 1 block/CU (8 waves, 2/SIMD)

// Implicit-GEMM conv3x3 + bias + pixel_shuffle quadrant, bf16 MFMA.
// Wave = 1 h-row x 64 w x 64 j, 0.5 ds_read/MFMA. Operand-swapped MFMA
// (mfma(B,A)) -> per-lane f32x4 = contiguous j-quad -> 16 dwordx4 stores,
// now NONTEMPORAL (bypass L2: the 604MB out stream was evicting the shared
// xb read set every ~13us; out is never re-read).
__global__ __launch_bounds__(512, 2) void conv_ps_kernel(
    const short* __restrict__ xb, const short* __restrict__ Wt,
    const float* __restrict__ bias, float* __restrict__ out)
{
    __shared__ short smem[A_SH + B_SH];
    short* As = smem;
    short* Bs = smem + A_SH;

    const int tid   = threadIdx.x;
    const int lane  = tid & 63;
    const int wv    = tid >> 6;       // which of 8 h-rows in the tile
    const int row_l = lane & 15;
    const int grp   = lane >> 4;
    const int b7    = row_l & 7;

    // XCD-aware bijective swizzle (nwg = 768 % 8 == 0); c innermost.
    const int raw = blockIdx.x;
    const int lb  = (raw & 7) * 96 + (raw >> 3);
    const int c   = lb & 3;
    const int wt  = (lb >> 2) % 3;
    const int hg  = (lb / 12) & 3;
    const int n   = lb / 48;
    const int w0  = wt * 64;
    const int hbase = hg * 48;
    const int q = c & 1, p = (c >> 1) & 1;

    // ---- prologue: A ring rows hbase-1 .. hbase+8 FIRST (HBM, long latency) ----
    for (int k = wv; k < 90; k += 8) {
        int rl  = k / 9, jj = k % 9;
        int row = hbase - 1 + rl;
        int slot = (row + 1) % RING;
        int cch = jj * 64 + lane;                  // 0..575 (valid < 528)
        int wpos = cch >> 3, g1 = cch & 7;
        int gs   = g1 ^ (wpos & 7);
        const short* src = xb + (((size_t)n * 194 + (row + 1)) * 194 + (w0 + wpos)) * 64 + gs * 8;
        void* dst = (char*)As + slot * 8448 + jj * 1024;
        if (jj < 8)            GLOAD_LDS16(src, dst);
        else if (lane < 16)    GLOAD_LDS16(src, dst);   // partial: 16 chunks
    }
    // ---- prologue: B (L2-resident after first blocks) ----
    {
        const short* wsrc = Wt + c * 4096;         // [t][c][j][ic], t-stride 16384
        for (int k = wv; k < 72; k += 8) {
            int t   = k >> 3, j8 = k & 7;
            int cch = j8 * 64 + lane;
            int j   = cch >> 3, s1 = cch & 7;
            int ss  = s1 ^ (j & 7);                // pre-swizzled source slot
            GLOAD_LDS16(wsrc + t * 16384 + j * 64 + ss * 8,
                        (char*)Bs + t * 8192 + j8 * 1024);
        }
    }
    __syncthreads();   // drains vmcnt -> prologue LDS complete

    // bias vector per nt: j0 = nt*16 + grp*4, components j0..j0+3 (oc = j*4+c)
    f32x4 bv4[4];
    #pragma unroll
    for (int nt = 0; nt < 4; ++nt) {
        const int j0 = nt * 16 + grp * 4;
        #pragma unroll
        for (int jv = 0; jv < 4; ++jv)
            bv4[nt][jv] = bias[(j0 + jv) * 4 + c];
    }

    #pragma unroll 1
    for (int it = 0; it < NT; ++it) {
        const int h0 = hbase + it * 8;

        // acc starts at bias (fused bias add); acc[mt][nt] = j-quad
        f32x4 acc[4][4];
        #pragma unroll
        for (int i = 0; i < 4; ++i)
            #pragma unroll
            for (int j = 0; j < 4; ++j)
                acc[i][j] = bv4[j];

        // compute: full K=576 for this wave's 64x64 tile, barrier-free
        int sl[3];
        #pragma unroll
        for (int dy = 0; dy < 3; ++dy) sl[dy] = (h0 + wv + dy) % RING;

        #pragma unroll
        for (int dy = 0; dy < 3; ++dy) {
            #pragma unroll
            for (int dx = 0; dx < 3; ++dx) {
                const int t  = dy * 3 + dx;
                const int rd = row_l + dx;
                const int a7 = rd & 7;
                const int aB = sl[dy] * A_SLOT + rd * 64;
                const int bB = t * 4096 + row_l * 64;
                #pragma unroll
                for (int ks = 0; ks < 2; ++ks) {
                    const int kg = ks * 4 + grp;
                    const short* ap = &As[aB + ((kg ^ a7) << 3)];
                    const short* bp = &Bs[bB + ((kg ^ b7) << 3)];
                    bf16x8 af[4], bfr[4];
                    #pragma unroll
                    for (int mt = 0; mt < 4; ++mt) af[mt]  = *(const bf16x8*)(ap + mt * 1024);
                    #pragma unroll
                    for (int nt = 0; nt < 4; ++nt) bfr[nt] = *(const bf16x8*)(bp + nt * 1024);
                    // swapped operands: D[j][w] so per-lane f32x4 is a j-quad
                    #pragma unroll
                    for (int mt = 0; mt < 4; ++mt)
                        #pragma unroll
                        for (int nt = 0; nt < 4; ++nt)
                            acc[mt][nt] = __builtin_amdgcn_mfma_f32_16x16x32_bf16(
                                bfr[nt], af[mt], acc[mt][nt], 0, 0, 0);
                }
            }
        }

        const int h = h0 + wv;
        const long rowb = ((long)(n * 384 + 2 * h + q)) * 384;

        if (it < NT - 1) {
            // 1. all waves done READING the ring
            asm volatile("s_waitcnt lgkmcnt(0)" ::: "memory");
            __builtin_amdgcn_sched_barrier(0);
            __builtin_amdgcn_s_barrier();
            __builtin_amdgcn_sched_barrier(0);

            // 2. issue refill: rows h0+9 .. h0+16 (8 rows x 9 instrs = 72)
            for (int k = wv; k < 72; k += 8) {
                int rl  = k / 9, jj = k % 9;
                int row = h0 + 9 + rl;
                int slot = (row + 1) % RING;
                int cch = jj * 64 + lane;
                int wpos = cch >> 3, g1 = cch & 7;
                int gs   = g1 ^ (wpos & 7);
                const short* src = xb + (((size_t)n * 194 + (row + 1)) * 194 + (w0 + wpos)) * 64 + gs * 8;
                void* dst = (char*)As + slot * 8448 + jj * 1024;
                if (jj < 8)         GLOAD_LDS16(src, dst);
                else if (lane < 16) GLOAD_LDS16(src, dst);
            }
            asm volatile("" ::: "memory");
            __builtin_amdgcn_sched_barrier(0);

            // 3. epilogue: 16 NONTEMPORAL dwordx4 stores (j-contiguous)
            #pragma unroll
            for (int mt = 0; mt < 4; ++mt) {
                float* po = out + ((rowb + 2 * (w0 + mt * 16 + row_l) + p) * 64 + grp * 4);
                #pragma unroll
                for (int nt = 0; nt < 4; ++nt)
                    __builtin_nontemporal_store(acc[mt][nt], (f32x4*)(po + nt * 16));
            }

            // 4. wait refills only (oldest 9 of this wave's VMEM ops)
            asm volatile("s_waitcnt vmcnt(15)" ::: "memory");
            __builtin_amdgcn_sched_barrier(0);
            __builtin_amdgcn_s_barrier();          // refilled rows visible
            __builtin_amdgcn_sched_barrier(0);
        } else {
            #pragma unroll
            for (int mt = 0; mt < 4; ++mt) {
                float* po = out + ((rowb + 2 * (w0 + mt * 16 + row_l) + p) * 64 + grp * 4);
                #pragma unroll
                for (int nt = 0; nt < 4; ++nt)
                    __builtin_nontemporal_store(acc[mt][nt], (f32x4*)(po + nt * 16));
            }
        }
    }
}

extern "C" void kernel_launch(void* const* d_in, const int* in_sizes, int n_in,
                              void* d_out, int out_size, void* d_ws, size_t ws_size,
                              hipStream_t stream) {
    const float* x = (const float*)d_in[0];
    const float* W = (const float*)d_in[1];
    const float* b = (const float*)d_in[2];
    float* out = (float*)d_out;

    const size_t xb_bytes = (size_t)16 * 194 * 194 * 64 * 2;   // 77,070,336 (padded)
    short* xbuf = (short*)d_ws;
    short* Wt   = (short*)((char*)d_ws + xb_bytes);

    hipLaunchKernelGGL(prep_kernel, dim3(2624), dim3(256), 0, stream, x, xbuf, W, Wt);
    hipLaunchKernelGGL(conv_ps_kernel, dim3(768), dim3(512), 0, stream, xbuf, Wt, b, out);
}